// Round 24
// baseline (109.084 us; speedup 1.0000x reference)
//
#include <hip/hip_runtime.h>
#include <hip/hip_bf16.h>

// S5 layer, MFMA pipeline (R23 + half-chunk g2 for 4 blocks/CU):
//   k0  : discretization, lambda power table, FRAGMENT-MAJOR bf16 operands
//   g1c : per-chunk FULL-N Bu GEMM (stage u once), scratch-free epilogue -> BuT
//   s1  : half-chunk finals from BuT (re-scan, bf16-consistent) -> st
//   s2  : cross-half-chunk state chain, 8-batched loads, IN-PLACE (st)
//   g2h : per-HALF-chunk scan (32 steps) + full-H GEMM + D*u (4 blocks/CU)

#define P_ 256
#define H_ 256
#define B_ 16
#define L_ 4096
#define NC 64               // chunks per batch (64 rows each)
#define NH 128              // half-chunks per batch

typedef __attribute__((ext_vector_type(8))) short short8v;
typedef __attribute__((ext_vector_type(4))) float f32x4;

// hardware v_cvt_pk_bf16_f32 via HIP intrinsic: a -> lo16, b -> hi16 (RNE)
static __device__ __forceinline__ unsigned cvtpk(float a, float b) {
    __hip_bfloat162 h = __float22bfloat162_rn(make_float2(a, b));
    unsigned r;
    __builtin_memcpy(&r, &h, 4);
    return r;
}

static __device__ __forceinline__ unsigned short f2bf(float f) {
    unsigned u = __float_as_uint(f);
    return (unsigned short)((u + 0x7fffu + ((u >> 16) & 1u)) >> 16);
}

// ---------------- k0: discretization + fragment-major operands + powers ----
// Bf: fragment (kt,nt): row r = nt*16+(l&15), k = kt*32+(l>>4)*8+j
// Cf: fragment (kt,ht): col h = ht*16+(l&15), q = kt*32+(l>>4)*8+j
// lamP [P][16] f32: {l, l4, l8, l12, l16, l32, l48, pad} as (re,im) pairs
__global__ __launch_bounds__(256) void k0_pre(
    const float* __restrict__ Lre, const float* __restrict__ Lim,
    const float* __restrict__ Bre, const float* __restrict__ Bim,
    const float* __restrict__ Cre, const float* __restrict__ Cim,
    const float* __restrict__ lstep,
    float* __restrict__ lam, float* __restrict__ lamP,
    unsigned short* __restrict__ Bf, unsigned short* __restrict__ Cf)
{
    int bx = blockIdx.x;
    int t  = threadIdx.x;
    {
        int p = bx, h = t;
        float laR = Lre[p], laI = Lim[p];
        float st = expf(lstep[p]);
        float er = expf(laR * st);
        float lr = er * cosf(laI * st);
        float li = er * sinf(laI * st);
        float den = laR * laR + laI * laI;
        float nr = lr - 1.0f, ni = li;
        float cr = (nr * laR + ni * laI) / den;
        float ci = (ni * laR - nr * laI) / den;
        float br = Bre[p * H_ + h], bi = Bim[p * H_ + h];
        float vre = cr * br - ci * bi;          // row 2p   (re)
        float vim = cr * bi + ci * br;          // row 2p+1 (im)
        int kt = h >> 5, lsl = ((h >> 3) & 3) << 4, j = h & 7;
        {
            int r = 2 * p;
            int lane = (r & 15) | lsl, nt = r >> 4;
            Bf[(((size_t)kt * 32 + nt) * 64 + lane) * 8 + j] = f2bf(vre);
        }
        {
            int r = 2 * p + 1;
            int lane = (r & 15) | lsl, nt = r >> 4;
            Bf[(((size_t)kt * 32 + nt) * 64 + lane) * 8 + j] = f2bf(vim);
        }
        if (t == 0) {
            lam[2 * p] = lr; lam[2 * p + 1] = li;
            float r2 = lr*lr - li*li,   i2 = 2.f*lr*li;
            float r4 = r2*r2 - i2*i2,   i4 = 2.f*r2*i2;
            float r8 = r4*r4 - i4*i4,   i8 = 2.f*r4*i4;
            float r12 = r8*r4 - i8*i4,  i12 = r8*i4 + i8*r4;
            float r16 = r8*r8 - i8*i8,  i16 = 2.f*r8*i8;
            float r32 = r16*r16 - i16*i16, i32 = 2.f*r16*i16;
            float r48 = r32*r16 - i32*i16, i48 = r32*i16 + i32*r16;
            float* lp = lamP + 16 * p;
            lp[0] = lr;  lp[1] = li;
            lp[2] = r4;  lp[3] = i4;
            lp[4] = r8;  lp[5] = i8;
            lp[6] = r12; lp[7] = i12;
            lp[8] = r16; lp[9] = i16;
            lp[10] = r32; lp[11] = i32;
            lp[12] = r48; lp[13] = i48;
            lp[14] = 0.f; lp[15] = 0.f;
        }
    }
    {
        int h = bx, p = t;
        float vre =  2.0f * Cre[h * P_ + p];    // q = 2p
        float vim = -2.0f * Cim[h * P_ + p];    // q = 2p+1
        int ht = h >> 4;
        #pragma unroll
        for (int e = 0; e < 2; ++e) {
            int q = 2 * p + e;
            int kt = q >> 5, lane = (h & 15) | (((q >> 3) & 3) << 4), j = q & 7;
            Cf[(((size_t)kt * 16 + ht) * 64 + lane) * 8 + j] = f2bf(e ? vim : vre);
        }
    }
}

// ---------------- g1c: per-chunk FULL-N Bu GEMM, scratch-free epilogue -----
// block = 64 u-rows x 512 N-cols; 8 waves, wave w owns cols w*64..w*64+63.
__global__ __launch_bounds__(512, 4) void g1c_gemm(
    const float* __restrict__ us,
    const unsigned short* __restrict__ Bf,
    unsigned* __restrict__ BuT)
{
    __shared__ __align__(16) char As[32768];   // 4 T-tiles x [64 rows][8x16B]
    int tid = threadIdx.x, w = tid >> 6, lane = tid & 63;
    int ci = blockIdx.x;                       // chunk index (segment-local)

    // stage A: batched loads, then convert+write (once per chunk)
    {
        const float4* ub = (const float4*)(us + (size_t)ci * 16384);
        float4 v[8];
        #pragma unroll
        for (int jj = 0; jj < 8; ++jj) v[jj] = ub[jj * 512 + tid];
        #pragma unroll
        for (int jj = 0; jj < 8; ++jj) {
            int f = jj * 512 + tid;            // 0..4095
            int r = f >> 6, c4 = f & 63;
            uint2 o;
            o.x = cvtpk(v[jj].x, v[jj].y);
            o.y = cvtpk(v[jj].z, v[jj].w);
            int pos = (((c4 >> 1) & 7) ^ (r & 7)) ^ (((c4 >> 5) & 1) << 2);
            *(uint2*)(As + (c4 >> 4) * 8192 + r * 128 + (pos << 4) + (c4 & 1) * 8) = o;
        }
    }

    int lr_ = lane & 15, lk = lane >> 4, r7 = lr_ & 7;
    bool evenl = (lr_ & 1) == 0;

    f32x4 acc[4][4];
    #pragma unroll
    for (int m = 0; m < 4; ++m)
        #pragma unroll
        for (int n = 0; n < 4; ++n)
            acc[m][n] = (f32x4){0.f, 0.f, 0.f, 0.f};

    __syncthreads();

    #pragma unroll
    for (int kt = 0; kt < 8; ++kt) {
        int T = kt >> 1;
        int q2 = (((kt & 1) * 4 + lk) ^ r7) ^ (((kt >> 2) & 1) << 2);
        short8v a_[4];
        #pragma unroll
        for (int m = 0; m < 4; ++m)
            a_[m] = *(const short8v*)(As + T * 8192 + (m * 16 + lr_) * 128 + (q2 << 4));
        #pragma unroll
        for (int n = 0; n < 4; ++n) {
            short8v b = *(const short8v*)(Bf + (((size_t)kt * 32 + w * 4 + n) * 64 + lane) * 8);
            #pragma unroll
            for (int m = 0; m < 4; ++m)
                acc[m][n] = __builtin_amdgcn_mfma_f32_16x16x32_bf16(a_[m], b, acc[m][n], 0, 0, 0);
        }
    }

    // scratch-free epilogue: static m indices, value-selected merge,
    // exec-predicated stores (each lane stores its 2 owned m's per n).
    size_t cb = (size_t)ci * 16384;            // 64*256 dwords per chunk
    #pragma unroll
    for (int n = 0; n < 4; ++n) {
        int p = w * 32 + n * 8 + (lr_ >> 1);
        #pragma unroll
        for (int m = 0; m < 4; ++m) {
            unsigned q0 = cvtpk(acc[m][n][0], acc[m][n][1]);
            unsigned q1 = cvtpk(acc[m][n][2], acc[m][n][3]);
            unsigned s0 = __shfl_xor(q0, 1);
            unsigned s1 = __shfl_xor(q1, 1);
            bool mine = evenl ? (m < 2) : (m >= 2);
            unsigned a0 = evenl ? q0 : s0, b0 = evenl ? s0 : q0;
            unsigned a1 = evenl ? q1 : s1, b1 = evenl ? s1 : q1;
            if (mine) {
                uint4 vv;
                vv.x = (a0 & 0xffffu) | (b0 << 16);
                vv.y = (a0 >> 16) | (b0 & 0xffff0000u);
                vv.z = (a1 & 0xffffu) | (b1 << 16);
                vv.w = (a1 >> 16) | (b1 & 0xffff0000u);
                *(uint4*)&BuT[cb + (size_t)p * 64 + m * 16 + lk * 4] = vv;
            }
        }
    }
}

// ---------------- s1: half-chunk finals from BuT (bf16-consistent) ---------
__global__ __launch_bounds__(256) void s1_finals(
    const unsigned* __restrict__ BuT, const float* __restrict__ lam,
    float2* __restrict__ st)
{
    int ci2 = blockIdx.x;                      // half-chunk index
    int p = threadIdx.x;
    int chunk = ci2 >> 1, half = ci2 & 1;
    const uint4* bp = (const uint4*)(BuT + (size_t)chunk * 16384 + (size_t)p * 64 + half * 32);
    uint4 dq[8];
    #pragma unroll
    for (int t = 0; t < 8; ++t) dq[t] = bp[t];
    float lr = lam[2 * p], li = lam[2 * p + 1];
    float fr = 0.f, fi = 0.f;
    #pragma unroll
    for (int t = 0; t < 8; ++t) {
        unsigned wv4[4] = {dq[t].x, dq[t].y, dq[t].z, dq[t].w};
        #pragma unroll
        for (int e = 0; e < 4; ++e) {
            unsigned wv = wv4[e];
            float ur = __uint_as_float(wv << 16);
            float ui = __uint_as_float(wv & 0xffff0000u);
            float nr = lr * fr - li * fi + ur;
            float ni = lr * fi + li * fr + ui;
            fr = nr; fi = ni;
        }
    }
    st[(size_t)ci2 * P_ + p] = make_float2(fr, fi);
}

// ---------------- s2: cross-half-chunk chain, batched loads, in-place ------
__global__ __launch_bounds__(256) void s2_chain(
    const float* __restrict__ lamP, float2* __restrict__ st)
{
    int bl = blockIdx.x;
    int p = threadIdx.x;
    float ar = lamP[16 * p + 10], ai = lamP[16 * p + 11];   // lambda^32
    float sr = 0.f, si = 0.f;
    float2* bp = st + (size_t)bl * NH * P_ + p;
    float2 f[8], fn[8];
    #pragma unroll
    for (int j = 0; j < 8; ++j) f[j] = bp[(size_t)j * P_];
    for (int c0 = 0; c0 < NH; c0 += 8) {
        if (c0 + 8 < NH) {
            #pragma unroll
            for (int j = 0; j < 8; ++j) fn[j] = bp[(size_t)(c0 + 8 + j) * P_];
        }
        #pragma unroll
        for (int j = 0; j < 8; ++j) {
            float2 t = f[j];
            bp[(size_t)(c0 + j) * P_] = make_float2(sr, si);
            float nr = ar * sr - ai * si + t.x;
            float ni = ar * si + ai * sr + t.y;
            sr = nr; si = ni;
        }
        #pragma unroll
        for (int j = 0; j < 8; ++j) f[j] = fn[j];
    }
}

// ---------------- g2h: per-HALF-chunk scan + full-H GEMM + D*u -------------
// block = 32 rows x H=256; 256 thr, 4 waves (wave w: h w*64..w*64+63);
// 32KB LDS -> 4 blocks/CU.
__global__ __launch_bounds__(256, 4) void g2h_gemm(
    const unsigned* __restrict__ BuT,
    const unsigned short* __restrict__ Cf,
    const float* __restrict__ lam, const float2* __restrict__ st,
    const float* __restrict__ useg, const float* __restrict__ Dv,
    float* __restrict__ yseg)
{
    __shared__ __align__(16) char xs[32768];   // 8 T-tiles x [32 rows][128B]
    int tid = threadIdx.x, w = tid >> 6, lane = tid & 63;
    int ci2 = blockIdx.x;                      // half-chunk index
    int chunk = ci2 >> 1, half = ci2 & 1;

    // phase 1: scan 32 steps, write x (bf16) to swizzled LDS
    {
        int p = tid;
        float lr = lam[2 * p], li = lam[2 * p + 1];
        float2 s0 = st[(size_t)ci2 * P_ + p];
        const uint4* bp = (const uint4*)(BuT + (size_t)chunk * 16384 + (size_t)p * 64 + half * 32);
        uint4 dq[8];
        #pragma unroll
        for (int t = 0; t < 8; ++t) dq[t] = bp[t];
        float xr = s0.x, xi = s0.y;
        int T = p >> 5, qd = (p & 31) >> 2, pos = p & 3;
        char* base = xs + T * 4096 + (pos << 2);
        #pragma unroll
        for (int t = 0; t < 8; ++t) {
            unsigned wv4[4] = {dq[t].x, dq[t].y, dq[t].z, dq[t].w};
            #pragma unroll
            for (int e = 0; e < 4; ++e) {
                int j = t * 4 + e;
                unsigned wv = wv4[e];
                float ur = __uint_as_float(wv << 16);
                float ui = __uint_as_float(wv & 0xffff0000u);
                float nr = lr * xr - li * xi + ur;
                float ni = lr * xi + li * xr + ui;
                xr = nr; xi = ni;
                *(unsigned*)(base + j * 128 + ((qd ^ (j & 7)) << 4)) = cvtpk(xr, xi);
            }
        }
    }
    __syncthreads();

    // phase 2: GEMM  y[32][256] = x[32][512] * Cf^T
    int lr_ = lane & 15, lk = lane >> 4, r7 = lr_ & 7;
    int h0 = w * 64;
    f32x4 acc[2][4];
    #pragma unroll
    for (int m = 0; m < 2; ++m)
        #pragma unroll
        for (int n = 0; n < 4; ++n)
            acc[m][n] = (f32x4){0.f, 0.f, 0.f, 0.f};

    #pragma unroll
    for (int kt = 0; kt < 16; ++kt) {
        int T = kt >> 1, q2 = (kt & 1) * 4 + lk;
        short8v a_[2];
        #pragma unroll
        for (int m = 0; m < 2; ++m)
            a_[m] = *(const short8v*)(xs + T * 4096 + (m * 16 + lr_) * 128 + ((q2 ^ r7) << 4));
        #pragma unroll
        for (int n = 0; n < 4; ++n) {
            short8v b = *(const short8v*)(Cf + (((size_t)kt * 16 + w * 4 + n) * 64 + lane) * 8);
            #pragma unroll
            for (int m = 0; m < 2; ++m)
                acc[m][n] = __builtin_amdgcn_mfma_f32_16x16x32_bf16(a_[m], b, acc[m][n], 0, 0, 0);
        }
    }

    float d_[4];
    #pragma unroll
    for (int n = 0; n < 4; ++n) d_[n] = Dv[h0 + n * 16 + lr_];
    #pragma unroll
    for (int m = 0; m < 2; ++m)
        #pragma unroll
        for (int n = 0; n < 4; ++n)
            #pragma unroll
            for (int i = 0; i < 4; ++i) {
                int rl = m * 16 + lk * 4 + i;
                int col = h0 + n * 16 + lr_;
                size_t off = ((size_t)ci2 * 32 + rl) * 256 + col;
                yseg[off] = acc[m][n][i] + d_[n] * useg[off];
            }
}

// ---------------- launch ----------------
extern "C" void kernel_launch(void* const* d_in, const int* in_sizes, int n_in,
                              void* d_out, int out_size, void* d_ws, size_t ws_size,
                              hipStream_t stream) {
    (void)in_sizes; (void)n_in; (void)out_size;
    const float* u    = (const float*)d_in[0];
    const float* Lre  = (const float*)d_in[1];
    const float* Lim  = (const float*)d_in[2];
    const float* Bre  = (const float*)d_in[3];
    const float* Bim  = (const float*)d_in[4];
    const float* Cre  = (const float*)d_in[5];
    const float* Cim  = (const float*)d_in[6];
    const float* Dv   = (const float*)d_in[7];
    const float* lstep= (const float*)d_in[8];

    // pick largest segment size the workspace allows
    const size_t fixed = 2048 + (size_t)16 * P_ * 4
                       + (size_t)512 * 256 * 2 + (size_t)256 * 512 * 2;
    const size_t perb = (size_t)L_ * 256 * 4 + (size_t)NH * P_ * 8;  // BuT + st
    int nb = 4;
    if (ws_size >= fixed + 16 * perb + 4096) nb = 16;
    else if (ws_size >= fixed + 8 * perb + 4096) nb = 8;
    int nseg = B_ / nb;

    char* w0 = (char*)d_ws;
    float* lam   = (float*)w0;  w0 += 2048;
    float* lamP  = (float*)w0;  w0 += (size_t)16 * P_ * 4;
    unsigned short* Bf = (unsigned short*)w0; w0 += (size_t)512 * 256 * 2;
    unsigned short* Cf = (unsigned short*)w0; w0 += (size_t)256 * 512 * 2;
    float2* st = (float2*)w0;   w0 += (size_t)nb * NH * P_ * 8;
    unsigned* BuT = (unsigned*)w0;

    k0_pre<<<256, 256, 0, stream>>>(Lre, Lim, Bre, Bim, Cre, Cim, lstep,
                                    lam, lamP, Bf, Cf);
    for (int s = 0; s < nseg; ++s) {
        const float* us = u + (size_t)s * nb * L_ * H_;
        float* ys = (float*)d_out + (size_t)s * nb * L_ * H_;
        g1c_gemm<<<nb * NC, 512, 0, stream>>>(us, Bf, BuT);
        s1_finals<<<nb * NH, 256, 0, stream>>>(BuT, lam, st);
        s2_chain<<<nb, 256, 0, stream>>>(lamP, st);
        g2h_gemm<<<nb * NH, 256, 0, stream>>>(BuT, Cf, lam, st, us, Dv, ys);
    }
}

// Round 25
// 103.603 us; speedup vs baseline: 1.0529x; 1.0529x over previous
//
#include <hip/hip_runtime.h>
#include <hip/hip_bf16.h>

// S5 layer, MFMA pipeline (best-known config, = R23):
//   k0  : discretization, lambda power table, FRAGMENT-MAJOR bf16 operands
//   g1c : per-chunk FULL-N Bu GEMM (stage u once), scratch-free epilogue -> BuT
//   s1  : half-chunk finals from BuT (re-scan, bf16-consistent) -> st
//   s2  : cross-half-chunk state chain, 8-batched loads, IN-PLACE (st)
//   g2s : per-chunk (both halves parallel) scan + full-H GEMM + D*u

#define P_ 256
#define H_ 256
#define B_ 16
#define L_ 4096
#define NC 64               // chunks per batch (64 rows each)
#define NH 128              // half-chunks per batch

typedef __attribute__((ext_vector_type(8))) short short8v;
typedef __attribute__((ext_vector_type(4))) float f32x4;

// hardware v_cvt_pk_bf16_f32 via HIP intrinsic: a -> lo16, b -> hi16 (RNE)
static __device__ __forceinline__ unsigned cvtpk(float a, float b) {
    __hip_bfloat162 h = __float22bfloat162_rn(make_float2(a, b));
    unsigned r;
    __builtin_memcpy(&r, &h, 4);
    return r;
}

static __device__ __forceinline__ unsigned short f2bf(float f) {
    unsigned u = __float_as_uint(f);
    return (unsigned short)((u + 0x7fffu + ((u >> 16) & 1u)) >> 16);
}

// ---------------- k0: discretization + fragment-major operands + powers ----
// Bf: fragment (kt,nt): row r = nt*16+(l&15), k = kt*32+(l>>4)*8+j
// Cf: fragment (kt,ht): col h = ht*16+(l&15), q = kt*32+(l>>4)*8+j
// lamP [P][16] f32: {l, l4, l8, l12, l16, l32, l48, pad} as (re,im) pairs
__global__ __launch_bounds__(256) void k0_pre(
    const float* __restrict__ Lre, const float* __restrict__ Lim,
    const float* __restrict__ Bre, const float* __restrict__ Bim,
    const float* __restrict__ Cre, const float* __restrict__ Cim,
    const float* __restrict__ lstep,
    float* __restrict__ lam, float* __restrict__ lamP,
    unsigned short* __restrict__ Bf, unsigned short* __restrict__ Cf)
{
    int bx = blockIdx.x;
    int t  = threadIdx.x;
    {
        int p = bx, h = t;
        float laR = Lre[p], laI = Lim[p];
        float st = expf(lstep[p]);
        float er = expf(laR * st);
        float lr = er * cosf(laI * st);
        float li = er * sinf(laI * st);
        float den = laR * laR + laI * laI;
        float nr = lr - 1.0f, ni = li;
        float cr = (nr * laR + ni * laI) / den;
        float ci = (ni * laR - nr * laI) / den;
        float br = Bre[p * H_ + h], bi = Bim[p * H_ + h];
        float vre = cr * br - ci * bi;          // row 2p   (re)
        float vim = cr * bi + ci * br;          // row 2p+1 (im)
        int kt = h >> 5, lsl = ((h >> 3) & 3) << 4, j = h & 7;
        {
            int r = 2 * p;
            int lane = (r & 15) | lsl, nt = r >> 4;
            Bf[(((size_t)kt * 32 + nt) * 64 + lane) * 8 + j] = f2bf(vre);
        }
        {
            int r = 2 * p + 1;
            int lane = (r & 15) | lsl, nt = r >> 4;
            Bf[(((size_t)kt * 32 + nt) * 64 + lane) * 8 + j] = f2bf(vim);
        }
        if (t == 0) {
            lam[2 * p] = lr; lam[2 * p + 1] = li;
            float r2 = lr*lr - li*li,   i2 = 2.f*lr*li;
            float r4 = r2*r2 - i2*i2,   i4 = 2.f*r2*i2;
            float r8 = r4*r4 - i4*i4,   i8 = 2.f*r4*i4;
            float r12 = r8*r4 - i8*i4,  i12 = r8*i4 + i8*r4;
            float r16 = r8*r8 - i8*i8,  i16 = 2.f*r8*i8;
            float r32 = r16*r16 - i16*i16, i32 = 2.f*r16*i16;
            float r48 = r32*r16 - i32*i16, i48 = r32*i16 + i32*r16;
            float* lp = lamP + 16 * p;
            lp[0] = lr;  lp[1] = li;
            lp[2] = r4;  lp[3] = i4;
            lp[4] = r8;  lp[5] = i8;
            lp[6] = r12; lp[7] = i12;
            lp[8] = r16; lp[9] = i16;
            lp[10] = r32; lp[11] = i32;
            lp[12] = r48; lp[13] = i48;
            lp[14] = 0.f; lp[15] = 0.f;
        }
    }
    {
        int h = bx, p = t;
        float vre =  2.0f * Cre[h * P_ + p];    // q = 2p
        float vim = -2.0f * Cim[h * P_ + p];    // q = 2p+1
        int ht = h >> 4;
        #pragma unroll
        for (int e = 0; e < 2; ++e) {
            int q = 2 * p + e;
            int kt = q >> 5, lane = (h & 15) | (((q >> 3) & 3) << 4), j = q & 7;
            Cf[(((size_t)kt * 16 + ht) * 64 + lane) * 8 + j] = f2bf(e ? vim : vre);
        }
    }
}

// ---------------- g1c: per-chunk FULL-N Bu GEMM, scratch-free epilogue -----
// block = 64 u-rows x 512 N-cols; 8 waves, wave w owns cols w*64..w*64+63.
__global__ __launch_bounds__(512, 4) void g1c_gemm(
    const float* __restrict__ us,
    const unsigned short* __restrict__ Bf,
    unsigned* __restrict__ BuT)
{
    __shared__ __align__(16) char As[32768];   // 4 T-tiles x [64 rows][8x16B]
    int tid = threadIdx.x, w = tid >> 6, lane = tid & 63;
    int ci = blockIdx.x;                       // chunk index (segment-local)

    // stage A: batched loads, then convert+write (once per chunk)
    {
        const float4* ub = (const float4*)(us + (size_t)ci * 16384);
        float4 v[8];
        #pragma unroll
        for (int jj = 0; jj < 8; ++jj) v[jj] = ub[jj * 512 + tid];
        #pragma unroll
        for (int jj = 0; jj < 8; ++jj) {
            int f = jj * 512 + tid;            // 0..4095
            int r = f >> 6, c4 = f & 63;
            uint2 o;
            o.x = cvtpk(v[jj].x, v[jj].y);
            o.y = cvtpk(v[jj].z, v[jj].w);
            int pos = (((c4 >> 1) & 7) ^ (r & 7)) ^ (((c4 >> 5) & 1) << 2);
            *(uint2*)(As + (c4 >> 4) * 8192 + r * 128 + (pos << 4) + (c4 & 1) * 8) = o;
        }
    }

    int lr_ = lane & 15, lk = lane >> 4, r7 = lr_ & 7;
    bool evenl = (lr_ & 1) == 0;

    f32x4 acc[4][4];
    #pragma unroll
    for (int m = 0; m < 4; ++m)
        #pragma unroll
        for (int n = 0; n < 4; ++n)
            acc[m][n] = (f32x4){0.f, 0.f, 0.f, 0.f};

    __syncthreads();

    #pragma unroll
    for (int kt = 0; kt < 8; ++kt) {
        int T = kt >> 1;
        int q2 = (((kt & 1) * 4 + lk) ^ r7) ^ (((kt >> 2) & 1) << 2);
        short8v a_[4];
        #pragma unroll
        for (int m = 0; m < 4; ++m)
            a_[m] = *(const short8v*)(As + T * 8192 + (m * 16 + lr_) * 128 + (q2 << 4));
        #pragma unroll
        for (int n = 0; n < 4; ++n) {
            short8v b = *(const short8v*)(Bf + (((size_t)kt * 32 + w * 4 + n) * 64 + lane) * 8);
            #pragma unroll
            for (int m = 0; m < 4; ++m)
                acc[m][n] = __builtin_amdgcn_mfma_f32_16x16x32_bf16(a_[m], b, acc[m][n], 0, 0, 0);
        }
    }

    // scratch-free epilogue: static m indices, value-selected merge,
    // exec-predicated stores (each lane stores its 2 owned m's per n).
    size_t cb = (size_t)ci * 16384;            // 64*256 dwords per chunk
    #pragma unroll
    for (int n = 0; n < 4; ++n) {
        int p = w * 32 + n * 8 + (lr_ >> 1);
        #pragma unroll
        for (int m = 0; m < 4; ++m) {
            unsigned q0 = cvtpk(acc[m][n][0], acc[m][n][1]);
            unsigned q1 = cvtpk(acc[m][n][2], acc[m][n][3]);
            unsigned s0 = __shfl_xor(q0, 1);
            unsigned s1 = __shfl_xor(q1, 1);
            bool mine = evenl ? (m < 2) : (m >= 2);
            unsigned a0 = evenl ? q0 : s0, b0 = evenl ? s0 : q0;
            unsigned a1 = evenl ? q1 : s1, b1 = evenl ? s1 : q1;
            if (mine) {
                uint4 vv;
                vv.x = (a0 & 0xffffu) | (b0 << 16);
                vv.y = (a0 >> 16) | (b0 & 0xffff0000u);
                vv.z = (a1 & 0xffffu) | (b1 << 16);
                vv.w = (a1 >> 16) | (b1 & 0xffff0000u);
                *(uint4*)&BuT[cb + (size_t)p * 64 + m * 16 + lk * 4] = vv;
            }
        }
    }
}

// ---------------- s1: half-chunk finals from BuT (bf16-consistent) ---------
__global__ __launch_bounds__(256) void s1_finals(
    const unsigned* __restrict__ BuT, const float* __restrict__ lam,
    float2* __restrict__ st)
{
    int ci2 = blockIdx.x;                      // half-chunk index
    int p = threadIdx.x;
    int chunk = ci2 >> 1, half = ci2 & 1;
    const uint4* bp = (const uint4*)(BuT + (size_t)chunk * 16384 + (size_t)p * 64 + half * 32);
    uint4 dq[8];
    #pragma unroll
    for (int t = 0; t < 8; ++t) dq[t] = bp[t];
    float lr = lam[2 * p], li = lam[2 * p + 1];
    float fr = 0.f, fi = 0.f;
    #pragma unroll
    for (int t = 0; t < 8; ++t) {
        unsigned wv4[4] = {dq[t].x, dq[t].y, dq[t].z, dq[t].w};
        #pragma unroll
        for (int e = 0; e < 4; ++e) {
            unsigned wv = wv4[e];
            float ur = __uint_as_float(wv << 16);
            float ui = __uint_as_float(wv & 0xffff0000u);
            float nr = lr * fr - li * fi + ur;
            float ni = lr * fi + li * fr + ui;
            fr = nr; fi = ni;
        }
    }
    st[(size_t)ci2 * P_ + p] = make_float2(fr, fi);
}

// ---------------- s2: cross-half-chunk chain, batched loads, in-place ------
__global__ __launch_bounds__(256) void s2_chain(
    const float* __restrict__ lamP, float2* __restrict__ st)
{
    int bl = blockIdx.x;
    int p = threadIdx.x;
    float ar = lamP[16 * p + 10], ai = lamP[16 * p + 11];   // lambda^32
    float sr = 0.f, si = 0.f;
    float2* bp = st + (size_t)bl * NH * P_ + p;
    float2 f[8], fn[8];
    #pragma unroll
    for (int j = 0; j < 8; ++j) f[j] = bp[(size_t)j * P_];
    for (int c0 = 0; c0 < NH; c0 += 8) {
        if (c0 + 8 < NH) {
            #pragma unroll
            for (int j = 0; j < 8; ++j) fn[j] = bp[(size_t)(c0 + 8 + j) * P_];
        }
        #pragma unroll
        for (int j = 0; j < 8; ++j) {
            float2 t = f[j];
            bp[(size_t)(c0 + j) * P_] = make_float2(sr, si);
            float nr = ar * sr - ai * si + t.x;
            float ni = ar * si + ai * sr + t.y;
            sr = nr; si = ni;
        }
        #pragma unroll
        for (int j = 0; j < 8; ++j) f[j] = fn[j];
    }
}

// ---------------- g2s: per-chunk scan (both halves) + full-H GEMM + D*u ----
// block = 64 rows x H=256; 512 thr; 64KB LDS -> 2 blocks/CU.
__global__ __launch_bounds__(512, 4) void g2s_gemm(
    const unsigned* __restrict__ BuT,
    const unsigned short* __restrict__ Cf,
    const float* __restrict__ lam, const float2* __restrict__ st,
    const float* __restrict__ useg, const float* __restrict__ Dv,
    float* __restrict__ yseg)
{
    __shared__ __align__(16) char xs[65536];   // [2 halves][8 T][32 rows][128B]
    int tid = threadIdx.x, w = tid >> 6, lane = tid & 63;
    int ci = blockIdx.x;

    // phase 1: both half-chunks scanned in parallel (512 threads = 2 x 256 p)
    {
        int p = tid & 255, half = tid >> 8;
        float lr = lam[2 * p], li = lam[2 * p + 1];
        float2 s0 = st[((size_t)ci * 2 + half) * P_ + p];
        const uint4* bp = (const uint4*)(BuT + (size_t)ci * 16384 + (size_t)p * 64 + half * 32);
        uint4 dq[8];
        #pragma unroll
        for (int t = 0; t < 8; ++t) dq[t] = bp[t];
        float xr = s0.x, xi = s0.y;
        int T = p >> 5, qd = (p & 31) >> 2, pos = p & 3;
        char* base = xs + half * 32768 + T * 4096 + (pos << 2);
        #pragma unroll
        for (int t = 0; t < 8; ++t) {
            unsigned wv4[4] = {dq[t].x, dq[t].y, dq[t].z, dq[t].w};
            #pragma unroll
            for (int e = 0; e < 4; ++e) {
                int j = t * 4 + e;
                unsigned wv = wv4[e];
                float ur = __uint_as_float(wv << 16);
                float ui = __uint_as_float(wv & 0xffff0000u);
                float nr = lr * xr - li * xi + ur;
                float ni = lr * xi + li * xr + ui;
                xr = nr; xi = ni;
                *(unsigned*)(base + j * 128 + ((qd ^ (j & 7)) << 4)) = cvtpk(xr, xi);
            }
        }
    }

    // phase 2: GEMM  y[64][256] = x[64][512] * Cf^T
    int lr_ = lane & 15, lk = lane >> 4, r7 = lr_ & 7;
    int h0 = w * 32;                           // 8 waves x 32 h-cols
    const unsigned short* cf0 = Cf + (((size_t)(w * 2 + 0)) * 64 + lane) * 8;
    const unsigned short* cf1 = Cf + (((size_t)(w * 2 + 1)) * 64 + lane) * 8;

    f32x4 acc[4][2];
    #pragma unroll
    for (int m = 0; m < 4; ++m)
        #pragma unroll
        for (int n = 0; n < 2; ++n)
            acc[m][n] = (f32x4){0.f, 0.f, 0.f, 0.f};

    short8v bcur[2], bnxt[2];
    bcur[0] = *(const short8v*)cf0;
    bcur[1] = *(const short8v*)cf1;
    __syncthreads();

    #pragma unroll
    for (int kt = 0; kt < 16; ++kt) {
        if (kt < 15) {                         // kt stride = 16*64*8 shorts
            bnxt[0] = *(const short8v*)(cf0 + (size_t)(kt + 1) * 8192);
            bnxt[1] = *(const short8v*)(cf1 + (size_t)(kt + 1) * 8192);
        }
        int T = kt >> 1, q2 = (kt & 1) * 4 + lk;
        short8v a_[4];
        #pragma unroll
        for (int m = 0; m < 4; ++m)
            a_[m] = *(const short8v*)(xs + (m >> 1) * 32768 + T * 4096
                                      + ((m & 1) * 16 + lr_) * 128 + ((q2 ^ r7) << 4));
        #pragma unroll
        for (int m = 0; m < 4; ++m)
            acc[m][0] = __builtin_amdgcn_mfma_f32_16x16x32_bf16(a_[m], bcur[0], acc[m][0], 0, 0, 0);
        #pragma unroll
        for (int m = 0; m < 4; ++m)
            acc[m][1] = __builtin_amdgcn_mfma_f32_16x16x32_bf16(a_[m], bcur[1], acc[m][1], 0, 0, 0);
        bcur[0] = bnxt[0]; bcur[1] = bnxt[1];
    }

    float d_[2];
    #pragma unroll
    for (int n = 0; n < 2; ++n) d_[n] = Dv[h0 + n * 16 + lr_];
    #pragma unroll
    for (int m = 0; m < 4; ++m)
        #pragma unroll
        for (int n = 0; n < 2; ++n)
            #pragma unroll
            for (int i = 0; i < 4; ++i) {
                int rl = m * 16 + lk * 4 + i;
                int col = h0 + n * 16 + lr_;
                size_t off = ((size_t)ci * 64 + rl) * 256 + col;
                yseg[off] = acc[m][n][i] + d_[n] * useg[off];
            }
}

// ---------------- launch ----------------
extern "C" void kernel_launch(void* const* d_in, const int* in_sizes, int n_in,
                              void* d_out, int out_size, void* d_ws, size_t ws_size,
                              hipStream_t stream) {
    (void)in_sizes; (void)n_in; (void)out_size;
    const float* u    = (const float*)d_in[0];
    const float* Lre  = (const float*)d_in[1];
    const float* Lim  = (const float*)d_in[2];
    const float* Bre  = (const float*)d_in[3];
    const float* Bim  = (const float*)d_in[4];
    const float* Cre  = (const float*)d_in[5];
    const float* Cim  = (const float*)d_in[6];
    const float* Dv   = (const float*)d_in[7];
    const float* lstep= (const float*)d_in[8];

    // pick largest segment size the workspace allows
    const size_t fixed = 2048 + (size_t)16 * P_ * 4
                       + (size_t)512 * 256 * 2 + (size_t)256 * 512 * 2;
    const size_t perb = (size_t)L_ * 256 * 4 + (size_t)NH * P_ * 8;  // BuT + st
    int nb = 4;
    if (ws_size >= fixed + 16 * perb + 4096) nb = 16;
    else if (ws_size >= fixed + 8 * perb + 4096) nb = 8;
    int nseg = B_ / nb;

    char* w0 = (char*)d_ws;
    float* lam   = (float*)w0;  w0 += 2048;
    float* lamP  = (float*)w0;  w0 += (size_t)16 * P_ * 4;
    unsigned short* Bf = (unsigned short*)w0; w0 += (size_t)512 * 256 * 2;
    unsigned short* Cf = (unsigned short*)w0; w0 += (size_t)256 * 512 * 2;
    float2* st = (float2*)w0;   w0 += (size_t)nb * NH * P_ * 8;
    unsigned* BuT = (unsigned*)w0;

    k0_pre<<<256, 256, 0, stream>>>(Lre, Lim, Bre, Bim, Cre, Cim, lstep,
                                    lam, lamP, Bf, Cf);
    for (int s = 0; s < nseg; ++s) {
        const float* us = u + (size_t)s * nb * L_ * H_;
        float* ys = (float*)d_out + (size_t)s * nb * L_ * H_;
        g1c_gemm<<<nb * NC, 512, 0, stream>>>(us, Bf, BuT);
        s1_finals<<<nb * NH, 256, 0, stream>>>(BuT, lam, st);
        s2_chain<<<nb, 256, 0, stream>>>(lamP, st);
        g2s_gemm<<<nb * NC, 512, 0, stream>>>(BuT, Cf, lam, st, us, Dv, ys);
    }
}